// Round 4
// baseline (303.383 us; speedup 1.0000x reference)
//
#include <hip/hip_runtime.h>

typedef unsigned short u16;
typedef __attribute__((ext_vector_type(8))) short bf16x8;
typedef __attribute__((ext_vector_type(4))) float f32x4;

__device__ __forceinline__ u16 f2bu(float f) {
  union { float f; unsigned u; } v; v.f = f;
  unsigned r = v.u + 0x7fffu + ((v.u >> 16) & 1u);
  return (u16)(r >> 16);
}
__device__ __forceinline__ float b2f(u16 s) {
  union { unsigned u; float f; } v; v.u = ((unsigned)s) << 16;
  return v.f;
}
__device__ __forceinline__ bf16x8 cvt8(float4 a, float4 b) {
  bf16x8 r;
  r[0] = (short)f2bu(a.x); r[1] = (short)f2bu(a.y);
  r[2] = (short)f2bu(a.z); r[3] = (short)f2bu(a.w);
  r[4] = (short)f2bu(b.x); r[5] = (short)f2bu(b.y);
  r[6] = (short)f2bu(b.z); r[7] = (short)f2bu(b.w);
  return r;
}
__device__ __forceinline__ f32x4 mfma16(bf16x8 a, bf16x8 b, f32x4 c) {
  return __builtin_amdgcn_mfma_f32_16x16x32_bf16(a, b, c, 0, 0, 0);
}

// ---------------- fp32 -> bf16 bulk convert (grid-stride, 8 elem/thread)
__global__ __launch_bounds__(256) void prep_bf16_k(const float* __restrict__ src,
                                                   u16* __restrict__ dst, int n) {
  int idx = (blockIdx.x * 256 + threadIdx.x) * 8;
  if (idx < n) {
    float4 a = *(const float4*)(src + idx);
    float4 b = *(const float4*)(src + idx + 4);
    *(bf16x8*)(dst + idx) = cvt8(a, b);
  }
}

// ---------------- table prep: bf16 table [160][64] (pad rows zero) + transpose [64][160]
__global__ void prep_table_k(const float* __restrict__ tbl,
                             u16* __restrict__ tb, u16* __restrict__ tbT) {
  int t = threadIdx.x;
  for (int idx = t; idx < 160 * 64; idx += 256) {
    int r = idx >> 6, d = idx & 63;
    float v = (r < 129) ? tbl[r * 64 + d] : 0.f;
    u16 bv = f2bu(v);
    tb[r * 64 + d] = bv;
    tbT[d * 160 + r] = bv;
  }
}

// ---------------- mask prep: int32 [4][1024][1024] -> bitmask (1 bit/elem, 512KB)
__global__ __launch_bounds__(256) void prep_mask_k(const int* __restrict__ mask,
                                                   unsigned long long* __restrict__ bm) {
  int idx = blockIdx.x * 256 + threadIdx.x;
  unsigned long long bits = __ballot(mask[idx] != 0);
  if ((threadIdx.x & 63) == 0) bm[idx >> 6] = bits;
}

// ---------------- QKV GEMM (bf16 in): C[4096][3072] = xb @ wb^T + b, scatter q/k/v
__global__ __launch_bounds__(256) void gemm_qkv_k(
    const u16* __restrict__ A, const u16* __restrict__ Bw,
    const float* __restrict__ bias,
    u16* __restrict__ qb, u16* __restrict__ kb, u16* __restrict__ vt) {
  __shared__ u16 As[128][40];
  __shared__ u16 Bs[128][40];
  const int tid = threadIdx.x;
  const int l = tid & 63, w = tid >> 6;
  const int wr = w >> 1, wc = w & 1;
  const int fr = l & 15, kq = (l >> 4) * 8;
  const int bid = blockIdx.x;
  const int tn = (bid % 24) * 128, tm = (bid / 24) * 128;
  const int sr = tid >> 1, sc = (tid & 1) * 16;
  const u16* Ag = A + (size_t)(tm + sr) * 1024 + sc;
  const u16* Bg = Bw + (size_t)(tn + sr) * 1024 + sc;
  f32x4 acc[4][4] = {};
  for (int kt = 0; kt < 32; ++kt) {
    bf16x8 a0 = *(const bf16x8*)(Ag + kt * 32);
    bf16x8 a1 = *(const bf16x8*)(Ag + kt * 32 + 8);
    bf16x8 b0 = *(const bf16x8*)(Bg + kt * 32);
    bf16x8 b1 = *(const bf16x8*)(Bg + kt * 32 + 8);
    __syncthreads();
    *(bf16x8*)&As[sr][sc] = a0;
    *(bf16x8*)&As[sr][sc + 8] = a1;
    *(bf16x8*)&Bs[sr][sc] = b0;
    *(bf16x8*)&Bs[sr][sc + 8] = b1;
    __syncthreads();
    bf16x8 af[4], bfv[4];
#pragma unroll
    for (int mi = 0; mi < 4; ++mi) af[mi] = *(const bf16x8*)&As[wr * 64 + mi * 16 + fr][kq];
#pragma unroll
    for (int ni = 0; ni < 4; ++ni) bfv[ni] = *(const bf16x8*)&Bs[wc * 64 + ni * 16 + fr][kq];
#pragma unroll
    for (int mi = 0; mi < 4; ++mi)
#pragma unroll
      for (int ni = 0; ni < 4; ++ni)
        acc[mi][ni] = mfma16(af[mi], bfv[ni], acc[mi][ni]);
  }
#pragma unroll
  for (int mi = 0; mi < 4; ++mi)
#pragma unroll
    for (int ni = 0; ni < 4; ++ni)
#pragma unroll
      for (int j = 0; j < 4; ++j) {
        int gm = tm + wr * 64 + mi * 16 + (l >> 4) * 4 + j;
        int gn = tn + wc * 64 + ni * 16 + fr;
        float v = acc[mi][ni][j] + bias[gn];
        int b = gm >> 10, s = gm & 1023;
        unsigned gnu = (unsigned)gn;
        unsigned h = gnu / 192u;
        unsigned rem = gnu - h * 192u;
        unsigned which = rem >> 6, d = rem & 63u;
        int bh = b * 16 + (int)h;
        u16 bv = f2bu(v);
        if (which == 0u)      qb[((size_t)bh * 1024 + s) * 64 + d] = bv;
        else if (which == 1u) kb[((size_t)bh * 1024 + s) * 64 + d] = bv;
        else                  vt[((size_t)bh * 64 + d) * 1024 + s] = bv;
      }
}

// ---------------- attention: 1 block = (b,h, 16 q-rows); 4 waves; 4 blocks/CU
#define PSTR 1032   // p-row stride u16: 2064B = 129 16B slots (odd -> conflict-free)
#define SSTR 136    // qs row stride u16: 272B = 17 slots (odd)
__global__ __launch_bounds__(256, 4) void attn_k(
    const u16* __restrict__ qb, const u16* __restrict__ kb,
    const u16* __restrict__ vt, const u16* __restrict__ tb,
    const u16* __restrict__ tbT, const unsigned* __restrict__ bmw,
    u16* __restrict__ vals) {
  __shared__ u16 pb[16 * PSTR];        // p~ (unnormalized, bf16)
  __shared__ u16 qs[16 * SSTR];        // pass0-1: qrel (bf16); pass2-3: band region
  __shared__ float wsum[4][16], wsumA[4][16], wsumB[4][16];
  const int tid = threadIdx.x;
  const int l = tid & 63, w = tid >> 6;
  const int fr = l & 15, g = l >> 4, kq = g * 8;
  const int blk = ((int)blockIdx.x & 7) * 512 + ((int)blockIdx.x >> 3);  // XCD swizzle
  const int qt = blk & 63, bh = blk >> 6;
  const int b = bh >> 4, h = bh & 15;
  const int qbase = qt * 16;
  const u16* qrow = qb + ((size_t)bh * 1024 + qbase) * 64;
  bf16x8 qa0 = *(const bf16x8*)(qrow + fr * 64 + kq);
  bf16x8 qa1 = *(const bf16x8*)(qrow + fr * 64 + 32 + kq);
  // preload mask bits: 4 rows x 256 cols (this wave's column range)
  const unsigned* bmb = bmw + ((size_t)b * 1024 + qbase) * 32 + w * 8;
  uint4 m0[4], m1[4];
#pragma unroll
  for (int j = 0; j < 4; ++j) {
    m0[j] = *(const uint4*)(bmb + (g * 4 + j) * 32);
    m1[j] = *(const uint4*)(bmb + (g * 4 + j) * 32 + 4);
  }
  // rank-1 table values for r=0 / r=128
  const int dcol = w * 16 + fr;
  const float t0v = b2f(tb[dcol]);
  const float t128v = b2f(tb[128 * 64 + dcol]);
  // pass 0: qrel[row][r] = q . table[r]  (stored bf16 in qs)
  for (int t = w; t < 9; t += 4) {
    int r0 = t * 16;
    const u16* tp = tb + (r0 + fr) * 64 + kq;
    bf16x8 tb0 = *(const bf16x8*)(tp);
    bf16x8 tb1 = *(const bf16x8*)(tp + 32);
    f32x4 acc = {0.f, 0.f, 0.f, 0.f};
    acc = mfma16(qa0, tb0, acc);
    acc = mfma16(qa1, tb1, acc);
    int rg = r0 + fr;
    if (rg < 129) {
#pragma unroll
      for (int j = 0; j < 4; ++j) qs[(g * 4 + j) * SSTR + rg] = f2bu(acc[j]);
    }
  }
  __syncthreads();
  // pass 1: QK^T + rel + mask + exp2, reg-prefetched K (chunks of 4 nt, depth-1)
  const u16* kbase = kb + (size_t)bh * 65536;
  const float C1 = 0.18033688011112042f;   // 0.125*log2(e)
  const float C2 = 17.31234049066756f;     // 12*log2(e)
  float ps[4] = {0.f, 0.f, 0.f, 0.f};
  float psA[4] = {0.f, 0.f, 0.f, 0.f};
  float psB[4] = {0.f, 0.f, 0.f, 0.f};
  bf16x8 kf[2][4][2];
#pragma unroll
  for (int i = 0; i < 4; ++i) {
    const u16* kp = kbase + (size_t)(w * 256 + i * 16 + fr) * 64 + kq;
    kf[0][i][0] = *(const bf16x8*)(kp);
    kf[0][i][1] = *(const bf16x8*)(kp + 32);
  }
#pragma unroll
  for (int c = 0; c < 4; ++c) {
    if (c < 3) {
#pragma unroll
      for (int i = 0; i < 4; ++i) {
        int nt = (c + 1) * 4 + i;
        const u16* kp = kbase + (size_t)(w * 256 + nt * 16 + fr) * 64 + kq;
        kf[(c + 1) & 1][i][0] = *(const bf16x8*)(kp);
        kf[(c + 1) & 1][i][1] = *(const bf16x8*)(kp + 32);
      }
    }
#pragma unroll
    for (int i = 0; i < 4; ++i) {
      int nt = c * 4 + i;
      int kgl = w * 256 + nt * 16 + fr;
      f32x4 acc = {0.f, 0.f, 0.f, 0.f};
      acc = mfma16(qa0, kf[c & 1][i][0], acc);
      acc = mfma16(qa1, kf[c & 1][i][1], acc);
#pragma unroll
      for (int j = 0; j < 4; ++j) {
        int row = g * 4 + j;
        int q = qbase + row;
        int dd = kgl - q;
        int rdx = dd < -64 ? 0 : (dd > 64 ? 128 : dd + 64);
        bool ov = (q >= 1 && q <= 1022);
        if (ov && kgl == 0) rdx = 0;
        if (ov && kgl == 1023) rdx = 128;
        float s = acc[j] + b2f(qs[row * SSTR + rdx]);
        unsigned word = (nt < 8) ? m0[j][nt >> 1] : m1[j][(nt >> 1) - 4];
        unsigned bit = (word >> ((nt & 1) * 16 + fr)) & 1u;
        float arg = bit ? __builtin_fmaf(s, C1, -C2) : -1e30f;
        float e = __builtin_amdgcn_exp2f(arg);
        ps[j] += e;
        psA[j] += (rdx == 0) ? e : 0.f;
        psB[j] += (rdx == 128) ? e : 0.f;
        pb[row * PSTR + kgl] = f2bu(e);
      }
    }
  }
#pragma unroll
  for (int j = 0; j < 4; ++j) {
#pragma unroll
    for (int off = 1; off <= 8; off <<= 1) {
      ps[j] += __shfl_xor(ps[j], off);
      psA[j] += __shfl_xor(psA[j], off);
      psB[j] += __shfl_xor(psB[j], off);
    }
  }
  if (fr == 0) {
#pragma unroll
    for (int j = 0; j < 4; ++j) {
      wsum[w][g * 4 + j] = ps[j];
      wsumA[w][g * 4 + j] = psA[j];
      wsumB[w][g * 4 + j] = psB[j];
    }
  }
  __syncthreads();   // qrel reads done -> qs reusable as band buffer
  // pass 2: fully parallel band gather into qs (r=0 zero; overridden edges zero)
  {
    int row2 = tid >> 4;
    int rb = (tid & 15) * 8;
    int q2 = qbase + row2;
    bool ov2 = (q2 >= 1 && q2 <= 1022);
    bf16x8 tmp;
#pragma unroll
    for (int i = 0; i < 8; ++i) {
      int r = rb + i;
      int k = q2 - 64 + r;
      int ksafe = k < 0 ? 0 : (k > 1023 ? 1023 : k);
      u16 val = pb[row2 * PSTR + ksafe];
      bool zero = (r == 0) || (k < 0) || (k > 1023) || (ov2 && (k == 0 || k == 1023));
      tmp[i] = zero ? (short)0 : (short)val;
    }
    *(bf16x8*)&qs[row2 * SSTR + rb] = tmp;
    if (tid < 16) {
      bf16x8 z = {};
      *(bf16x8*)&qs[tid * SSTR + 128] = z;
    }
  }
  __syncthreads();
  // pass 3: PV (p~ x V^T) + band (s~ x table) + rank-1 r=0/128, scale by 1/sum
  f32x4 acc = {0.f, 0.f, 0.f, 0.f};
  const u16* vbase = vt + (size_t)bh * 65536;
  const u16* arow = pb + fr * PSTR + kq;
  const u16* vrow = vbase + (size_t)dcol * 1024 + kq;
  bf16x8 tf[4];
#pragma unroll
  for (int i = 0; i < 4; ++i) tf[i] = *(const bf16x8*)(tbT + dcol * 160 + kq + i * 32);
  bf16x8 vf[2][4];
#pragma unroll
  for (int i = 0; i < 4; ++i) vf[0][i] = *(const bf16x8*)(vrow + i * 32);
#pragma unroll
  for (int cc = 0; cc < 8; ++cc) {
    if (cc < 7) {
#pragma unroll
      for (int i = 0; i < 4; ++i)
        vf[(cc + 1) & 1][i] = *(const bf16x8*)(vrow + ((cc + 1) * 4 + i) * 32);
    }
#pragma unroll
    for (int i = 0; i < 4; ++i) {
      int kc = cc * 4 + i;
      bf16x8 a = *(const bf16x8*)(arow + kc * 32);
      acc = mfma16(a, vf[cc & 1][i], acc);
    }
  }
  const u16* srow = qs + fr * SSTR + kq;
#pragma unroll
  for (int kc = 0; kc < 4; ++kc) {
    bf16x8 a = *(const bf16x8*)(srow + kc * 32);
    acc = mfma16(a, tf[kc], acc);
  }
#pragma unroll
  for (int j = 0; j < 4; ++j) {
    int row = g * 4 + j;
    float tot = wsum[0][row] + wsum[1][row] + wsum[2][row] + wsum[3][row];
    float sAt = wsumA[0][row] + wsumA[1][row] + wsumA[2][row] + wsumA[3][row];
    float sBt = wsumB[0][row] + wsumB[1][row] + wsumB[2][row] + wsumB[3][row];
    float val = (acc[j] + sAt * t0v + sBt * t128v) / tot;
    int sg = qbase + row;
    vals[((size_t)b * 1024 + sg) * 1024 + h * 64 + dcol] = f2bu(val);
  }
}

// ---------------- output GEMM: out[4096][1024] = vals(bf16) @ owb^T + o_b  (fp32 out)
__global__ __launch_bounds__(256) void gemm_out_k(
    const u16* __restrict__ A, const u16* __restrict__ Bw,
    const float* __restrict__ bias, float* __restrict__ out) {
  __shared__ u16 As[128][40];
  __shared__ u16 Bs[128][40];
  const int tid = threadIdx.x;
  const int l = tid & 63, w = tid >> 6;
  const int wr = w >> 1, wc = w & 1;
  const int fr = l & 15, kq = (l >> 4) * 8;
  const int bid = blockIdx.x;
  const int tn = (bid % 8) * 128, tm = (bid / 8) * 128;
  const int sr = tid >> 1, sc = (tid & 1) * 16;
  const u16* Ag = A + (size_t)(tm + sr) * 1024 + sc;
  const u16* Bg = Bw + (size_t)(tn + sr) * 1024 + sc;
  f32x4 acc[4][4] = {};
  for (int kt = 0; kt < 32; ++kt) {
    bf16x8 a0 = *(const bf16x8*)(Ag + kt * 32);
    bf16x8 a1 = *(const bf16x8*)(Ag + kt * 32 + 8);
    bf16x8 b0 = *(const bf16x8*)(Bg + kt * 32);
    bf16x8 b1 = *(const bf16x8*)(Bg + kt * 32 + 8);
    __syncthreads();
    *(bf16x8*)&As[sr][sc] = a0;
    *(bf16x8*)&As[sr][sc + 8] = a1;
    *(bf16x8*)&Bs[sr][sc] = b0;
    *(bf16x8*)&Bs[sr][sc + 8] = b1;
    __syncthreads();
    bf16x8 af[4], bfv[4];
#pragma unroll
    for (int mi = 0; mi < 4; ++mi) af[mi] = *(const bf16x8*)&As[wr * 64 + mi * 16 + fr][kq];
#pragma unroll
    for (int ni = 0; ni < 4; ++ni) bfv[ni] = *(const bf16x8*)&Bs[wc * 64 + ni * 16 + fr][kq];
#pragma unroll
    for (int mi = 0; mi < 4; ++mi)
#pragma unroll
      for (int ni = 0; ni < 4; ++ni)
        acc[mi][ni] = mfma16(af[mi], bfv[ni], acc[mi][ni]);
  }
#pragma unroll
  for (int mi = 0; mi < 4; ++mi)
#pragma unroll
    for (int ni = 0; ni < 4; ++ni)
#pragma unroll
      for (int j = 0; j < 4; ++j) {
        int gm = tm + wr * 64 + mi * 16 + (l >> 4) * 4 + j;
        int gn = tn + wc * 64 + ni * 16 + fr;
        out[(size_t)gm * 1024 + gn] = acc[mi][ni][j] + bias[gn];
      }
}

extern "C" void kernel_launch(void* const* d_in, const int* in_sizes, int n_in,
                              void* d_out, int out_size, void* d_ws, size_t ws_size,
                              hipStream_t stream) {
  (void)in_sizes; (void)n_in; (void)out_size; (void)ws_size;
  const float* x    = (const float*)d_in[0];
  const float* qkvw = (const float*)d_in[1];
  const float* qkvb = (const float*)d_in[2];
  const float* ow   = (const float*)d_in[3];
  const float* ob   = (const float*)d_in[4];
  const float* tbl  = (const float*)d_in[5];
  const int*   mask = (const int*)d_in[6];
  float* out = (float*)d_out;
  char* ws = (char*)d_ws;
  u16* tb   = (u16*)(ws);
  u16* tbT  = (u16*)(ws + 20480);
  u16* qb   = (u16*)(ws + 40960);
  u16* kb   = (u16*)(ws + 40960 + 8388608ull);
  u16* vt   = (u16*)(ws + 40960 + 2ull * 8388608ull);
  u16* xbvals = (u16*)(ws + 40960 + 3ull * 8388608ull);   // xb (pre-attn) / vals (post)
  unsigned long long* bm = (unsigned long long*)(ws + 40960 + 4ull * 8388608ull);
  u16* wb   = (u16*)(ws + 40960 + 4ull * 8388608ull + 524288ull);
  u16* owb  = (u16*)(ws + 40960 + 4ull * 8388608ull + 524288ull + 6291456ull);

  prep_table_k<<<dim3(1), dim3(256), 0, stream>>>(tbl, tb, tbT);
  prep_mask_k<<<dim3(16384), dim3(256), 0, stream>>>(mask, bm);
  prep_bf16_k<<<dim3(2048), dim3(256), 0, stream>>>(x, xbvals, 4194304);
  prep_bf16_k<<<dim3(1536), dim3(256), 0, stream>>>(qkvw, wb, 3145728);
  prep_bf16_k<<<dim3(512), dim3(256), 0, stream>>>(ow, owb, 1048576);
  gemm_qkv_k<<<dim3(768), dim3(256), 0, stream>>>(xbvals, wb, qkvb, qb, kb, vt);
  attn_k<<<dim3(4096), dim3(256), 0, stream>>>(qb, kb, vt, tb, tbT, (const unsigned*)bm, xbvals);
  gemm_out_k<<<dim3(256), dim3(256), 0, stream>>>(xbvals, owb, ob, out);
}

// Round 5
// 265.782 us; speedup vs baseline: 1.1415x; 1.1415x over previous
//
#include <hip/hip_runtime.h>

typedef unsigned short u16;
typedef __attribute__((ext_vector_type(8))) short bf16x8;
typedef __attribute__((ext_vector_type(4))) float f32x4;

__device__ __forceinline__ u16 f2bu(float f) {
  union { float f; unsigned u; } v; v.f = f;
  unsigned r = v.u + 0x7fffu + ((v.u >> 16) & 1u);
  return (u16)(r >> 16);
}
__device__ __forceinline__ float b2f(u16 s) {
  union { unsigned u; float f; } v; v.u = ((unsigned)s) << 16;
  return v.f;
}
__device__ __forceinline__ bf16x8 cvt8(float4 a, float4 b) {
  bf16x8 r;
  r[0] = (short)f2bu(a.x); r[1] = (short)f2bu(a.y);
  r[2] = (short)f2bu(a.z); r[3] = (short)f2bu(a.w);
  r[4] = (short)f2bu(b.x); r[5] = (short)f2bu(b.y);
  r[6] = (short)f2bu(b.z); r[7] = (short)f2bu(b.w);
  return r;
}
__device__ __forceinline__ f32x4 mfma16(bf16x8 a, bf16x8 b, f32x4 c) {
  return __builtin_amdgcn_mfma_f32_16x16x32_bf16(a, b, c, 0, 0, 0);
}

// ---------------- fp32 -> bf16 bulk convert (grid-stride, 8 elem/thread)
__global__ __launch_bounds__(256) void prep_bf16_k(const float* __restrict__ src,
                                                   u16* __restrict__ dst, int n) {
  int idx = (blockIdx.x * 256 + threadIdx.x) * 8;
  if (idx < n) {
    float4 a = *(const float4*)(src + idx);
    float4 b = *(const float4*)(src + idx + 4);
    *(bf16x8*)(dst + idx) = cvt8(a, b);
  }
}

// ---------------- table prep: bf16 table [160][64] (pad rows zero) + transpose [64][160]
__global__ void prep_table_k(const float* __restrict__ tbl,
                             u16* __restrict__ tb, u16* __restrict__ tbT) {
  int t = threadIdx.x;
  for (int idx = t; idx < 160 * 64; idx += 256) {
    int r = idx >> 6, d = idx & 63;
    float v = (r < 129) ? tbl[r * 64 + d] : 0.f;
    u16 bv = f2bu(v);
    tb[r * 64 + d] = bv;
    tbT[d * 160 + r] = bv;
  }
}

// ---------------- mask prep: int32 [4][1024][1024] -> bitmask (1 bit/elem, 512KB)
__global__ __launch_bounds__(256) void prep_mask_k(const int* __restrict__ mask,
                                                   unsigned long long* __restrict__ bm) {
  int idx = blockIdx.x * 256 + threadIdx.x;
  unsigned long long bits = __ballot(mask[idx] != 0);
  if ((threadIdx.x & 63) == 0) bm[idx >> 6] = bits;
}

// ---------------- QKV GEMM (bf16 in): C[4096][3072] = xb @ wb^T + b, scatter q/k/v
__global__ __launch_bounds__(256) void gemm_qkv_k(
    const u16* __restrict__ A, const u16* __restrict__ Bw,
    const float* __restrict__ bias,
    u16* __restrict__ qb, u16* __restrict__ kb, u16* __restrict__ vt) {
  __shared__ u16 As[128][40];
  __shared__ u16 Bs[128][40];
  const int tid = threadIdx.x;
  const int l = tid & 63, w = tid >> 6;
  const int wr = w >> 1, wc = w & 1;
  const int fr = l & 15, kq = (l >> 4) * 8;
  const int bid = blockIdx.x;
  const int tn = (bid % 24) * 128, tm = (bid / 24) * 128;
  const int sr = tid >> 1, sc = (tid & 1) * 16;
  const u16* Ag = A + (size_t)(tm + sr) * 1024 + sc;
  const u16* Bg = Bw + (size_t)(tn + sr) * 1024 + sc;
  f32x4 acc[4][4] = {};
  for (int kt = 0; kt < 32; ++kt) {
    bf16x8 a0 = *(const bf16x8*)(Ag + kt * 32);
    bf16x8 a1 = *(const bf16x8*)(Ag + kt * 32 + 8);
    bf16x8 b0 = *(const bf16x8*)(Bg + kt * 32);
    bf16x8 b1 = *(const bf16x8*)(Bg + kt * 32 + 8);
    __syncthreads();
    *(bf16x8*)&As[sr][sc] = a0;
    *(bf16x8*)&As[sr][sc + 8] = a1;
    *(bf16x8*)&Bs[sr][sc] = b0;
    *(bf16x8*)&Bs[sr][sc + 8] = b1;
    __syncthreads();
    bf16x8 af[4], bfv[4];
#pragma unroll
    for (int mi = 0; mi < 4; ++mi) af[mi] = *(const bf16x8*)&As[wr * 64 + mi * 16 + fr][kq];
#pragma unroll
    for (int ni = 0; ni < 4; ++ni) bfv[ni] = *(const bf16x8*)&Bs[wc * 64 + ni * 16 + fr][kq];
#pragma unroll
    for (int mi = 0; mi < 4; ++mi)
#pragma unroll
      for (int ni = 0; ni < 4; ++ni)
        acc[mi][ni] = mfma16(af[mi], bfv[ni], acc[mi][ni]);
  }
#pragma unroll
  for (int mi = 0; mi < 4; ++mi)
#pragma unroll
    for (int ni = 0; ni < 4; ++ni)
#pragma unroll
      for (int j = 0; j < 4; ++j) {
        int gm = tm + wr * 64 + mi * 16 + (l >> 4) * 4 + j;
        int gn = tn + wc * 64 + ni * 16 + fr;
        float v = acc[mi][ni][j] + bias[gn];
        int b = gm >> 10, s = gm & 1023;
        unsigned gnu = (unsigned)gn;
        unsigned h = gnu / 192u;
        unsigned rem = gnu - h * 192u;
        unsigned which = rem >> 6, d = rem & 63u;
        int bh = b * 16 + (int)h;
        u16 bv = f2bu(v);
        if (which == 0u)      qb[((size_t)bh * 1024 + s) * 64 + d] = bv;
        else if (which == 1u) kb[((size_t)bh * 1024 + s) * 64 + d] = bv;
        else                  vt[((size_t)bh * 64 + d) * 1024 + s] = bv;
      }
}

// ---------------- attention: 1 block = (b,h, 16 q-rows); 4 waves
#define PSTR 1032   // p-row stride u16: 2064B = 129 16B slots (odd -> conflict-free)
#define SSTR 136    // qs row stride u16: 272B = 17 slots (odd)
__global__ __launch_bounds__(256) void attn_k(
    const u16* __restrict__ qb, const u16* __restrict__ kb,
    const u16* __restrict__ vt, const u16* __restrict__ tb,
    const u16* __restrict__ tbT, const unsigned* __restrict__ bmw,
    u16* __restrict__ vals) {
  __shared__ u16 pb[16 * PSTR];        // p~ (unnormalized, bf16)
  __shared__ u16 qs[16 * SSTR];        // pass0-1: qrel (bf16); pass2-3: band region
  __shared__ float wsum[4][16], wsumA[4][16], wsumB[4][16];
  const int tid = threadIdx.x;
  const int l = tid & 63, w = tid >> 6;
  const int fr = l & 15, g = l >> 4, kq = g * 8;
  const int blk = ((int)blockIdx.x & 7) * 512 + ((int)blockIdx.x >> 3);  // XCD swizzle
  const int qt = blk & 63, bh = blk >> 6;
  const int b = bh >> 4, h = bh & 15;
  const int qbase = qt * 16;
  const u16* qrow = qb + ((size_t)bh * 1024 + qbase) * 64;
  bf16x8 qa0 = *(const bf16x8*)(qrow + fr * 64 + kq);
  bf16x8 qa1 = *(const bf16x8*)(qrow + fr * 64 + 32 + kq);
  // preload mask bits: 4 rows x 256 cols (this wave's column range)
  const unsigned* bmb = bmw + ((size_t)b * 1024 + qbase) * 32 + w * 8;
  uint4 m0[4], m1[4];
#pragma unroll
  for (int j = 0; j < 4; ++j) {
    m0[j] = *(const uint4*)(bmb + (g * 4 + j) * 32);
    m1[j] = *(const uint4*)(bmb + (g * 4 + j) * 32 + 4);
  }
  // rank-1 table values for r=0 / r=128
  const int dcol = w * 16 + fr;
  const float t0v = b2f(tb[dcol]);
  const float t128v = b2f(tb[128 * 64 + dcol]);
  // pass 0: qrel[row][r] = q . table[r]  (stored bf16 in qs)
  for (int t = w; t < 9; t += 4) {
    int r0 = t * 16;
    const u16* tp = tb + (r0 + fr) * 64 + kq;
    bf16x8 tb0 = *(const bf16x8*)(tp);
    bf16x8 tb1 = *(const bf16x8*)(tp + 32);
    f32x4 acc = {0.f, 0.f, 0.f, 0.f};
    acc = mfma16(qa0, tb0, acc);
    acc = mfma16(qa1, tb1, acc);
    int rg = r0 + fr;
    if (rg < 129) {
#pragma unroll
      for (int j = 0; j < 4; ++j) qs[(g * 4 + j) * SSTR + rg] = f2bu(acc[j]);
    }
  }
  __syncthreads();
  // hoist qrel saturated values (r=0 / r=128) into registers
  float q0r[4], q128r[4];
#pragma unroll
  for (int j = 0; j < 4; ++j) {
    int row = g * 4 + j;
    q0r[j] = b2f(qs[row * SSTR]);
    q128r[j] = b2f(qs[row * SSTR + 128]);
  }
  // pass 1: QK^T + rel + mask + exp2; chunk-of-2 depth-1 K prefetch;
  // wave-uniform band test: out-of-band tiles use q0r/q128r registers (no LDS)
  const u16* kbase = kb + (size_t)bh * 65536;
  const float C1 = 0.18033688011112042f;   // 0.125*log2(e)
  const float C2 = 17.31234049066756f;     // 12*log2(e)
  float ps[4] = {0.f, 0.f, 0.f, 0.f};
  float psA[4] = {0.f, 0.f, 0.f, 0.f};
  float psB[4] = {0.f, 0.f, 0.f, 0.f};
  bf16x8 kf[2][2][2];
#pragma unroll
  for (int i = 0; i < 2; ++i) {
    const u16* kp = kbase + (size_t)(w * 256 + i * 16 + fr) * 64 + kq;
    kf[0][i][0] = *(const bf16x8*)(kp);
    kf[0][i][1] = *(const bf16x8*)(kp + 32);
  }
#pragma unroll
  for (int c = 0; c < 8; ++c) {
    if (c < 7) {
#pragma unroll
      for (int i = 0; i < 2; ++i) {
        int nt = (c + 1) * 2 + i;
        const u16* kp = kbase + (size_t)(w * 256 + nt * 16 + fr) * 64 + kq;
        kf[(c + 1) & 1][i][0] = *(const bf16x8*)(kp);
        kf[(c + 1) & 1][i][1] = *(const bf16x8*)(kp + 32);
      }
    }
#pragma unroll
    for (int i = 0; i < 2; ++i) {
      int nt = c * 2 + i;
      int ncol = w * 256 + nt * 16;
      int kgl = ncol + fr;
      f32x4 acc = {0.f, 0.f, 0.f, 0.f};
      acc = mfma16(qa0, kf[c & 1][i][0], acc);
      acc = mfma16(qa1, kf[c & 1][i][1], acc);
      if (ncol + 79 <= qbase) {            // entire tile: dd <= -64 -> rdx = 0
#pragma unroll
        for (int j = 0; j < 4; ++j) {
          float s = acc[j] + q0r[j];
          unsigned word = (nt < 8) ? m0[j][nt >> 1] : m1[j][(nt >> 1) - 4];
          unsigned bit = (word >> ((nt & 1) * 16 + fr)) & 1u;
          float arg = bit ? __builtin_fmaf(s, C1, -C2) : -1e30f;
          float e = __builtin_amdgcn_exp2f(arg);
          ps[j] += e; psA[j] += e;
          pb[(g * 4 + j) * PSTR + kgl] = f2bu(e);
        }
      } else if (ncol >= qbase + 79) {     // entire tile: dd >= 64 -> rdx = 128
#pragma unroll
        for (int j = 0; j < 4; ++j) {
          float s = acc[j] + q128r[j];
          unsigned word = (nt < 8) ? m0[j][nt >> 1] : m1[j][(nt >> 1) - 4];
          unsigned bit = (word >> ((nt & 1) * 16 + fr)) & 1u;
          float arg = bit ? __builtin_fmaf(s, C1, -C2) : -1e30f;
          float e = __builtin_amdgcn_exp2f(arg);
          ps[j] += e; psB[j] += e;
          pb[(g * 4 + j) * PSTR + kgl] = f2bu(e);
        }
      } else {                              // mixed tile: full per-element path
#pragma unroll
        for (int j = 0; j < 4; ++j) {
          int row = g * 4 + j;
          int q = qbase + row;
          int dd = kgl - q;
          int rdx = dd < -64 ? 0 : (dd > 64 ? 128 : dd + 64);
          bool ov = (q >= 1 && q <= 1022);
          if (ov && kgl == 0) rdx = 0;
          if (ov && kgl == 1023) rdx = 128;
          float s = acc[j] + b2f(qs[row * SSTR + rdx]);
          unsigned word = (nt < 8) ? m0[j][nt >> 1] : m1[j][(nt >> 1) - 4];
          unsigned bit = (word >> ((nt & 1) * 16 + fr)) & 1u;
          float arg = bit ? __builtin_fmaf(s, C1, -C2) : -1e30f;
          float e = __builtin_amdgcn_exp2f(arg);
          ps[j] += e;
          psA[j] += (rdx == 0) ? e : 0.f;
          psB[j] += (rdx == 128) ? e : 0.f;
          pb[row * PSTR + kgl] = f2bu(e);
        }
      }
    }
  }
#pragma unroll
  for (int j = 0; j < 4; ++j) {
#pragma unroll
    for (int off = 1; off <= 8; off <<= 1) {
      ps[j] += __shfl_xor(ps[j], off);
      psA[j] += __shfl_xor(psA[j], off);
      psB[j] += __shfl_xor(psB[j], off);
    }
  }
  if (fr == 0) {
#pragma unroll
    for (int j = 0; j < 4; ++j) {
      wsum[w][g * 4 + j] = ps[j];
      wsumA[w][g * 4 + j] = psA[j];
      wsumB[w][g * 4 + j] = psB[j];
    }
  }
  __syncthreads();   // qrel reads done -> qs reusable as band buffer
  // pass 2: fully parallel band gather into qs (r=0 zero; overridden edges zero)
  {
    int row2 = tid >> 4;
    int rb = (tid & 15) * 8;
    int q2 = qbase + row2;
    bool ov2 = (q2 >= 1 && q2 <= 1022);
    bf16x8 tmp;
#pragma unroll
    for (int i = 0; i < 8; ++i) {
      int r = rb + i;
      int k = q2 - 64 + r;
      int ksafe = k < 0 ? 0 : (k > 1023 ? 1023 : k);
      u16 val = pb[row2 * PSTR + ksafe];
      bool zero = (r == 0) || (k < 0) || (k > 1023) || (ov2 && (k == 0 || k == 1023));
      tmp[i] = zero ? (short)0 : (short)val;
    }
    *(bf16x8*)&qs[row2 * SSTR + rb] = tmp;
    if (tid < 16) {
      bf16x8 z = {};
      *(bf16x8*)&qs[tid * SSTR + 128] = z;
    }
  }
  __syncthreads();
  // pass 3: PV (p~ x V^T) + band (s~ x table) + rank-1 r=0/128, scale by 1/sum
  f32x4 acc = {0.f, 0.f, 0.f, 0.f};
  const u16* vbase = vt + (size_t)bh * 65536;
  const u16* arow = pb + fr * PSTR + kq;
  const u16* vrow = vbase + (size_t)dcol * 1024 + kq;
  bf16x8 tf[4];
#pragma unroll
  for (int i = 0; i < 4; ++i) tf[i] = *(const bf16x8*)(tbT + dcol * 160 + kq + i * 32);
  bf16x8 vf[2][4];
#pragma unroll
  for (int i = 0; i < 4; ++i) vf[0][i] = *(const bf16x8*)(vrow + i * 32);
#pragma unroll
  for (int cc = 0; cc < 8; ++cc) {
    if (cc < 7) {
#pragma unroll
      for (int i = 0; i < 4; ++i)
        vf[(cc + 1) & 1][i] = *(const bf16x8*)(vrow + ((cc + 1) * 4 + i) * 32);
    }
#pragma unroll
    for (int i = 0; i < 4; ++i) {
      int kc = cc * 4 + i;
      bf16x8 a = *(const bf16x8*)(arow + kc * 32);
      acc = mfma16(a, vf[cc & 1][i], acc);
    }
  }
  const u16* srow = qs + fr * SSTR + kq;
#pragma unroll
  for (int kc = 0; kc < 4; ++kc) {
    bf16x8 a = *(const bf16x8*)(srow + kc * 32);
    acc = mfma16(a, tf[kc], acc);
  }
#pragma unroll
  for (int j = 0; j < 4; ++j) {
    int row = g * 4 + j;
    float tot = wsum[0][row] + wsum[1][row] + wsum[2][row] + wsum[3][row];
    float sAt = wsumA[0][row] + wsumA[1][row] + wsumA[2][row] + wsumA[3][row];
    float sBt = wsumB[0][row] + wsumB[1][row] + wsumB[2][row] + wsumB[3][row];
    float val = (acc[j] + sAt * t0v + sBt * t128v) / tot;
    int sg = qbase + row;
    vals[((size_t)b * 1024 + sg) * 1024 + h * 64 + dcol] = f2bu(val);
  }
}

// ---------------- output GEMM: out[4096][1024] = vals(bf16) @ owb^T + o_b  (fp32 out)
__global__ __launch_bounds__(256) void gemm_out_k(
    const u16* __restrict__ A, const u16* __restrict__ Bw,
    const float* __restrict__ bias, float* __restrict__ out) {
  __shared__ u16 As[128][40];
  __shared__ u16 Bs[128][40];
  const int tid = threadIdx.x;
  const int l = tid & 63, w = tid >> 6;
  const int wr = w >> 1, wc = w & 1;
  const int fr = l & 15, kq = (l >> 4) * 8;
  const int bid = blockIdx.x;
  const int tn = (bid % 8) * 128, tm = (bid / 8) * 128;
  const int sr = tid >> 1, sc = (tid & 1) * 16;
  const u16* Ag = A + (size_t)(tm + sr) * 1024 + sc;
  const u16* Bg = Bw + (size_t)(tn + sr) * 1024 + sc;
  f32x4 acc[4][4] = {};
  for (int kt = 0; kt < 32; ++kt) {
    bf16x8 a0 = *(const bf16x8*)(Ag + kt * 32);
    bf16x8 a1 = *(const bf16x8*)(Ag + kt * 32 + 8);
    bf16x8 b0 = *(const bf16x8*)(Bg + kt * 32);
    bf16x8 b1 = *(const bf16x8*)(Bg + kt * 32 + 8);
    __syncthreads();
    *(bf16x8*)&As[sr][sc] = a0;
    *(bf16x8*)&As[sr][sc + 8] = a1;
    *(bf16x8*)&Bs[sr][sc] = b0;
    *(bf16x8*)&Bs[sr][sc + 8] = b1;
    __syncthreads();
    bf16x8 af[4], bfv[4];
#pragma unroll
    for (int mi = 0; mi < 4; ++mi) af[mi] = *(const bf16x8*)&As[wr * 64 + mi * 16 + fr][kq];
#pragma unroll
    for (int ni = 0; ni < 4; ++ni) bfv[ni] = *(const bf16x8*)&Bs[wc * 64 + ni * 16 + fr][kq];
#pragma unroll
    for (int mi = 0; mi < 4; ++mi)
#pragma unroll
      for (int ni = 0; ni < 4; ++ni)
        acc[mi][ni] = mfma16(af[mi], bfv[ni], acc[mi][ni]);
  }
#pragma unroll
  for (int mi = 0; mi < 4; ++mi)
#pragma unroll
    for (int ni = 0; ni < 4; ++ni)
#pragma unroll
      for (int j = 0; j < 4; ++j) {
        int gm = tm + wr * 64 + mi * 16 + (l >> 4) * 4 + j;
        int gn = tn + wc * 64 + ni * 16 + fr;
        out[(size_t)gm * 1024 + gn] = acc[mi][ni][j] + bias[gn];
      }
}

extern "C" void kernel_launch(void* const* d_in, const int* in_sizes, int n_in,
                              void* d_out, int out_size, void* d_ws, size_t ws_size,
                              hipStream_t stream) {
  (void)in_sizes; (void)n_in; (void)out_size; (void)ws_size;
  const float* x    = (const float*)d_in[0];
  const float* qkvw = (const float*)d_in[1];
  const float* qkvb = (const float*)d_in[2];
  const float* ow   = (const float*)d_in[3];
  const float* ob   = (const float*)d_in[4];
  const float* tbl  = (const float*)d_in[5];
  const int*   mask = (const int*)d_in[6];
  float* out = (float*)d_out;
  char* ws = (char*)d_ws;
  u16* tb   = (u16*)(ws);
  u16* tbT  = (u16*)(ws + 20480);
  u16* qb   = (u16*)(ws + 40960);
  u16* kb   = (u16*)(ws + 40960 + 8388608ull);
  u16* vt   = (u16*)(ws + 40960 + 2ull * 8388608ull);
  u16* xbvals = (u16*)(ws + 40960 + 3ull * 8388608ull);   // xb (pre-attn) / vals (post)
  unsigned long long* bm = (unsigned long long*)(ws + 40960 + 4ull * 8388608ull);
  u16* wb   = (u16*)(ws + 40960 + 4ull * 8388608ull + 524288ull);
  u16* owb  = (u16*)(ws + 40960 + 4ull * 8388608ull + 524288ull + 6291456ull);

  prep_table_k<<<dim3(1), dim3(256), 0, stream>>>(tbl, tb, tbT);
  prep_mask_k<<<dim3(16384), dim3(256), 0, stream>>>(mask, bm);
  prep_bf16_k<<<dim3(2048), dim3(256), 0, stream>>>(x, xbvals, 4194304);
  prep_bf16_k<<<dim3(1536), dim3(256), 0, stream>>>(qkvw, wb, 3145728);
  prep_bf16_k<<<dim3(512), dim3(256), 0, stream>>>(ow, owb, 1048576);
  gemm_qkv_k<<<dim3(768), dim3(256), 0, stream>>>(xbvals, wb, qkvb, qb, kb, vt);
  attn_k<<<dim3(4096), dim3(256), 0, stream>>>(qb, kb, vt, tb, tbT, (const unsigned*)bm, xbvals);
  gemm_out_k<<<dim3(256), dim3(256), 0, stream>>>(xbvals, owb, ob, out);
}

// Round 6
// 257.684 us; speedup vs baseline: 1.1773x; 1.0314x over previous
//
#include <hip/hip_runtime.h>

typedef unsigned short u16;
typedef __attribute__((ext_vector_type(8))) short bf16x8;
typedef __attribute__((ext_vector_type(4))) float f32x4;

__device__ __forceinline__ u16 f2bu(float f) {
  union { float f; unsigned u; } v; v.f = f;
  unsigned r = v.u + 0x7fffu + ((v.u >> 16) & 1u);
  return (u16)(r >> 16);
}
__device__ __forceinline__ u16 f2bu_fast(float f) {   // round-half-up, 2 ops
  union { float f; unsigned u; } v; v.f = f;
  return (u16)((v.u + 0x8000u) >> 16);
}
__device__ __forceinline__ float b2f(u16 s) {
  union { unsigned u; float f; } v; v.u = ((unsigned)s) << 16;
  return v.f;
}
__device__ __forceinline__ bf16x8 cvt8(float4 a, float4 b) {
  bf16x8 r;
  r[0] = (short)f2bu(a.x); r[1] = (short)f2bu(a.y);
  r[2] = (short)f2bu(a.z); r[3] = (short)f2bu(a.w);
  r[4] = (short)f2bu(b.x); r[5] = (short)f2bu(b.y);
  r[6] = (short)f2bu(b.z); r[7] = (short)f2bu(b.w);
  return r;
}
__device__ __forceinline__ f32x4 mfma16(bf16x8 a, bf16x8 b, f32x4 c) {
  return __builtin_amdgcn_mfma_f32_16x16x32_bf16(a, b, c, 0, 0, 0);
}

// ---------------- fp32 -> bf16 bulk convert (8 elem/thread)
__global__ __launch_bounds__(256) void prep_bf16_k(const float* __restrict__ src,
                                                   u16* __restrict__ dst, int n) {
  int idx = (blockIdx.x * 256 + threadIdx.x) * 8;
  if (idx < n) {
    float4 a = *(const float4*)(src + idx);
    float4 b = *(const float4*)(src + idx + 4);
    *(bf16x8*)(dst + idx) = cvt8(a, b);
  }
}

// ---------------- table prep: bf16 table [160][64] (pad rows zero) + transpose [64][160]
__global__ void prep_table_k(const float* __restrict__ tbl,
                             u16* __restrict__ tb, u16* __restrict__ tbT) {
  int t = threadIdx.x;
  for (int idx = t; idx < 160 * 64; idx += 256) {
    int r = idx >> 6, d = idx & 63;
    float v = (r < 129) ? tbl[r * 64 + d] : 0.f;
    u16 bv = f2bu(v);
    tb[r * 64 + d] = bv;
    tbT[d * 160 + r] = bv;
  }
}

// ---------------- mask prep: int32 [4][1024][1024] -> transposed 16-bit words
// bmq[b][q][w][fr] bit nt = mask[b][q][w*256 + nt*16 + fr]
__global__ __launch_bounds__(256) void prep_maskq_k(const int* __restrict__ mask,
                                                    u16* __restrict__ bmq) {
  int t = blockIdx.x * 256 + threadIdx.x;     // 262144 total
  int fr = t & 15, wv = (t >> 4) & 3;
  int q = (t >> 6) & 1023, b = t >> 16;
  const int* mrow = mask + ((size_t)b * 1024 + q) * 1024 + wv * 256 + fr;
  unsigned bits = 0;
#pragma unroll
  for (int nt = 0; nt < 16; ++nt) bits |= (mrow[nt * 16] != 0 ? 1u : 0u) << nt;
  bmq[t] = (u16)bits;
}

// ---------------- QKV GEMM (bf16 in): C[4096][3072] = xb @ wb^T + b, scatter q/k/v
__global__ __launch_bounds__(256) void gemm_qkv_k(
    const u16* __restrict__ A, const u16* __restrict__ Bw,
    const float* __restrict__ bias,
    u16* __restrict__ qb, u16* __restrict__ kb, u16* __restrict__ vt) {
  __shared__ u16 As[128][40];
  __shared__ u16 Bs[128][40];
  const int tid = threadIdx.x;
  const int l = tid & 63, w = tid >> 6;
  const int wr = w >> 1, wc = w & 1;
  const int fr = l & 15, kq = (l >> 4) * 8;
  const int bid = blockIdx.x;
  const int tn = (bid % 24) * 128, tm = (bid / 24) * 128;
  const int sr = tid >> 1, sc = (tid & 1) * 16;
  const u16* Ag = A + (size_t)(tm + sr) * 1024 + sc;
  const u16* Bg = Bw + (size_t)(tn + sr) * 1024 + sc;
  f32x4 acc[4][4] = {};
  for (int kt = 0; kt < 32; ++kt) {
    bf16x8 a0 = *(const bf16x8*)(Ag + kt * 32);
    bf16x8 a1 = *(const bf16x8*)(Ag + kt * 32 + 8);
    bf16x8 b0 = *(const bf16x8*)(Bg + kt * 32);
    bf16x8 b1 = *(const bf16x8*)(Bg + kt * 32 + 8);
    __syncthreads();
    *(bf16x8*)&As[sr][sc] = a0;
    *(bf16x8*)&As[sr][sc + 8] = a1;
    *(bf16x8*)&Bs[sr][sc] = b0;
    *(bf16x8*)&Bs[sr][sc + 8] = b1;
    __syncthreads();
    bf16x8 af[4], bfv[4];
#pragma unroll
    for (int mi = 0; mi < 4; ++mi) af[mi] = *(const bf16x8*)&As[wr * 64 + mi * 16 + fr][kq];
#pragma unroll
    for (int ni = 0; ni < 4; ++ni) bfv[ni] = *(const bf16x8*)&Bs[wc * 64 + ni * 16 + fr][kq];
#pragma unroll
    for (int mi = 0; mi < 4; ++mi)
#pragma unroll
      for (int ni = 0; ni < 4; ++ni)
        acc[mi][ni] = mfma16(af[mi], bfv[ni], acc[mi][ni]);
  }
#pragma unroll
  for (int mi = 0; mi < 4; ++mi)
#pragma unroll
    for (int ni = 0; ni < 4; ++ni)
#pragma unroll
      for (int j = 0; j < 4; ++j) {
        int gm = tm + wr * 64 + mi * 16 + (l >> 4) * 4 + j;
        int gn = tn + wc * 64 + ni * 16 + fr;
        float v = acc[mi][ni][j] + bias[gn];
        int b = gm >> 10, s = gm & 1023;
        unsigned gnu = (unsigned)gn;
        unsigned h = gnu / 192u;
        unsigned rem = gnu - h * 192u;
        unsigned which = rem >> 6, d = rem & 63u;
        int bh = b * 16 + (int)h;
        u16 bv = f2bu(v);
        if (which == 0u)      qb[((size_t)bh * 1024 + s) * 64 + d] = bv;
        else if (which == 1u) kb[((size_t)bh * 1024 + s) * 64 + d] = bv;
        else                  vt[((size_t)bh * 64 + d) * 1024 + s] = bv;
      }
}

// ---------------- attention: 1 block = (b,h, 16 q-rows); 4 waves
#define PSTR 1032   // p-row stride u16: 2064B = 129 16B slots (odd -> conflict-free)
#define SSTR 136    // qs row stride u16: 272B = 17 slots (odd)
__global__ __launch_bounds__(256) void attn_k(
    const u16* __restrict__ qb, const u16* __restrict__ kb,
    const u16* __restrict__ vt, const u16* __restrict__ tb,
    const u16* __restrict__ tbT, const u16* __restrict__ bmq,
    u16* __restrict__ vals) {
  __shared__ u16 pb[16 * PSTR];        // p~ (unnormalized, bf16)
  __shared__ u16 qs[16 * SSTR];        // pass0-1: qrel (bf16); pass2-3: band region
  __shared__ float wsum[4][16], wsumA[4][16], wsumB[4][16];
  const int tid = threadIdx.x;
  const int l = tid & 63, w = tid >> 6;
  const int fr = l & 15, g = l >> 4, kq = g * 8;
  const int blk = ((int)blockIdx.x & 7) * 512 + ((int)blockIdx.x >> 3);  // XCD swizzle
  const int qt = blk & 63, bh = blk >> 6;
  const int b = bh >> 4, h = bh & 15;
  const int qbase = qt * 16;
  const u16* qrow = qb + ((size_t)bh * 1024 + qbase) * 64;
  bf16x8 qa0 = *(const bf16x8*)(qrow + fr * 64 + kq);
  bf16x8 qa1 = *(const bf16x8*)(qrow + fr * 64 + 32 + kq);
  // mask bits: per row j, 16-bit word (bit nt = col w*256+nt*16+fr)
  unsigned bits[4];
#pragma unroll
  for (int j = 0; j < 4; ++j)
    bits[j] = bmq[(((size_t)b * 1024 + qbase + g * 4 + j) * 4 + w) * 16 + fr];
  // rank-1 table values for r=0 / r=128
  const int dcol = w * 16 + fr;
  const float t0v = b2f(tb[dcol]);
  const float t128v = b2f(tb[128 * 64 + dcol]);
  // pass 0: qrel[row][r] = q . table[r]  (stored bf16 in qs)
  for (int t = w; t < 9; t += 4) {
    int r0 = t * 16;
    const u16* tp = tb + (r0 + fr) * 64 + kq;
    bf16x8 tb0 = *(const bf16x8*)(tp);
    bf16x8 tb1 = *(const bf16x8*)(tp + 32);
    f32x4 acc = {0.f, 0.f, 0.f, 0.f};
    acc = mfma16(qa0, tb0, acc);
    acc = mfma16(qa1, tb1, acc);
    int rg = r0 + fr;
    if (rg < 129) {
#pragma unroll
      for (int j = 0; j < 4; ++j) qs[(g * 4 + j) * SSTR + rg] = f2bu(acc[j]);
    }
  }
  __syncthreads();
  // hoist qrel saturated values (r=0 / r=128) into registers
  float q0r[4], q128r[4];
#pragma unroll
  for (int j = 0; j < 4; ++j) {
    int row = g * 4 + j;
    q0r[j] = b2f(qs[row * SSTR]);
    q128r[j] = b2f(qs[row * SSTR + 128]);
  }
  // pass 1: QK^T + rel + mask + exp2; ROLLED loop, X/Y chunk rotation, depth-1
  const u16* kbase = kb + (size_t)bh * 65536;
  const float C1 = 0.18033688011112042f;   // 0.125*log2(e)
  const float C2 = 17.31234049066756f;     // 12*log2(e)
  float ps[4] = {0.f, 0.f, 0.f, 0.f};
  float psA[4] = {0.f, 0.f, 0.f, 0.f};
  float psB[4] = {0.f, 0.f, 0.f, 0.f};
  auto ldK = [&](int nt, bf16x8& lo, bf16x8& hi) {
    const u16* kp = kbase + (size_t)(w * 256 + nt * 16 + fr) * 64 + kq;
    lo = *(const bf16x8*)(kp);
    hi = *(const bf16x8*)(kp + 32);
  };
  auto tileC = [&](int nt, bf16x8 k0, bf16x8 k1) {
    int ncol = w * 256 + nt * 16;
    int kgl = ncol + fr;
    f32x4 acc = {0.f, 0.f, 0.f, 0.f};
    acc = mfma16(qa0, k0, acc);
    acc = mfma16(qa1, k1, acc);
    if (ncol + 79 <= qbase) {            // whole tile: dd <= -64 -> rdx = 0
#pragma unroll
      for (int j = 0; j < 4; ++j) {
        float s = acc[j] + q0r[j];
        float arg = ((bits[j] >> nt) & 1u) ? __builtin_fmaf(s, C1, -C2) : -1e30f;
        float e = __builtin_amdgcn_exp2f(arg);
        ps[j] += e; psA[j] += e;
        pb[(g * 4 + j) * PSTR + kgl] = f2bu_fast(e);
      }
    } else if (ncol >= qbase + 79) {     // whole tile: dd >= 64 -> rdx = 128
#pragma unroll
      for (int j = 0; j < 4; ++j) {
        float s = acc[j] + q128r[j];
        float arg = ((bits[j] >> nt) & 1u) ? __builtin_fmaf(s, C1, -C2) : -1e30f;
        float e = __builtin_amdgcn_exp2f(arg);
        ps[j] += e; psB[j] += e;
        pb[(g * 4 + j) * PSTR + kgl] = f2bu_fast(e);
      }
    } else {                              // mixed tile: per-element rdx
#pragma unroll
      for (int j = 0; j < 4; ++j) {
        int row = g * 4 + j;
        int q = qbase + row;
        int dd = kgl - q;
        int rdx = dd < -64 ? 0 : (dd > 64 ? 128 : dd + 64);
        bool ov = (q >= 1 && q <= 1022);
        if (ov && kgl == 0) rdx = 0;
        if (ov && kgl == 1023) rdx = 128;
        float s = acc[j] + b2f(qs[row * SSTR + rdx]);
        float arg = ((bits[j] >> nt) & 1u) ? __builtin_fmaf(s, C1, -C2) : -1e30f;
        float e = __builtin_amdgcn_exp2f(arg);
        ps[j] += e;
        psA[j] += (rdx == 0) ? e : 0.f;
        psB[j] += (rdx == 128) ? e : 0.f;
        pb[row * PSTR + kgl] = f2bu_fast(e);
      }
    }
  };
  {
    bf16x8 xa0, xa1, xb0, xb1, ya0, ya1, yb0, yb1;
    ldK(0, xa0, xa1); ldK(1, xb0, xb1);
#pragma unroll 1
    for (int cp = 0; cp < 4; ++cp) {
      int base = cp * 4;
      ldK(base + 2, ya0, ya1); ldK(base + 3, yb0, yb1);
      tileC(base + 0, xa0, xa1); tileC(base + 1, xb0, xb1);
      if (cp < 3) { ldK(base + 4, xa0, xa1); ldK(base + 5, xb0, xb1); }
      tileC(base + 2, ya0, ya1); tileC(base + 3, yb0, yb1);
    }
  }
#pragma unroll
  for (int j = 0; j < 4; ++j) {
#pragma unroll
    for (int off = 1; off <= 8; off <<= 1) {
      ps[j] += __shfl_xor(ps[j], off);
      psA[j] += __shfl_xor(psA[j], off);
      psB[j] += __shfl_xor(psB[j], off);
    }
  }
  if (fr == 0) {
#pragma unroll
    for (int j = 0; j < 4; ++j) {
      wsum[w][g * 4 + j] = ps[j];
      wsumA[w][g * 4 + j] = psA[j];
      wsumB[w][g * 4 + j] = psB[j];
    }
  }
  __syncthreads();   // qrel reads done -> qs reusable as band buffer
  // pass 2: fully parallel band gather into qs (r=0 zero; overridden edges zero)
  {
    int row2 = tid >> 4;
    int rb = (tid & 15) * 8;
    int q2 = qbase + row2;
    bool ov2 = (q2 >= 1 && q2 <= 1022);
    bf16x8 tmp;
#pragma unroll
    for (int i = 0; i < 8; ++i) {
      int r = rb + i;
      int k = q2 - 64 + r;
      int ksafe = k < 0 ? 0 : (k > 1023 ? 1023 : k);
      u16 val = pb[row2 * PSTR + ksafe];
      bool zero = (r == 0) || (k < 0) || (k > 1023) || (ov2 && (k == 0 || k == 1023));
      tmp[i] = zero ? (short)0 : (short)val;
    }
    *(bf16x8*)&qs[row2 * SSTR + rb] = tmp;
    if (tid < 16) {
      bf16x8 z = {};
      *(bf16x8*)&qs[tid * SSTR + 128] = z;
    }
  }
  __syncthreads();
  // pass 3: PV (p~ x V^T) + band (s~ x table) + rank-1 r=0/128, scale by 1/sum
  f32x4 acc = {0.f, 0.f, 0.f, 0.f};
  const u16* vbase = vt + (size_t)bh * 65536;
  const u16* arow = pb + fr * PSTR + kq;
  const u16* vrow = vbase + (size_t)dcol * 1024 + kq;
  bf16x8 tf[4];
#pragma unroll
  for (int i = 0; i < 4; ++i) tf[i] = *(const bf16x8*)(tbT + dcol * 160 + kq + i * 32);
  {
    bf16x8 x0, x1, x2, x3, y0, y1, y2, y3;
    x0 = *(const bf16x8*)(vrow);       x1 = *(const bf16x8*)(vrow + 32);
    x2 = *(const bf16x8*)(vrow + 64);  x3 = *(const bf16x8*)(vrow + 96);
#pragma unroll 1
    for (int cp = 0; cp < 4; ++cp) {
      int base = cp * 8;
      y0 = *(const bf16x8*)(vrow + (base + 4) * 32);
      y1 = *(const bf16x8*)(vrow + (base + 5) * 32);
      y2 = *(const bf16x8*)(vrow + (base + 6) * 32);
      y3 = *(const bf16x8*)(vrow + (base + 7) * 32);
      acc = mfma16(*(const bf16x8*)(arow + (base + 0) * 32), x0, acc);
      acc = mfma16(*(const bf16x8*)(arow + (base + 1) * 32), x1, acc);
      acc = mfma16(*(const bf16x8*)(arow + (base + 2) * 32), x2, acc);
      acc = mfma16(*(const bf16x8*)(arow + (base + 3) * 32), x3, acc);
      if (cp < 3) {
        x0 = *(const bf16x8*)(vrow + (base + 8) * 32);
        x1 = *(const bf16x8*)(vrow + (base + 9) * 32);
        x2 = *(const bf16x8*)(vrow + (base + 10) * 32);
        x3 = *(const bf16x8*)(vrow + (base + 11) * 32);
      }
      acc = mfma16(*(const bf16x8*)(arow + (base + 4) * 32), y0, acc);
      acc = mfma16(*(const bf16x8*)(arow + (base + 5) * 32), y1, acc);
      acc = mfma16(*(const bf16x8*)(arow + (base + 6) * 32), y2, acc);
      acc = mfma16(*(const bf16x8*)(arow + (base + 7) * 32), y3, acc);
    }
  }
  const u16* srow = qs + fr * SSTR + kq;
#pragma unroll
  for (int kc = 0; kc < 4; ++kc) {
    bf16x8 a = *(const bf16x8*)(srow + kc * 32);
    acc = mfma16(a, tf[kc], acc);
  }
#pragma unroll
  for (int j = 0; j < 4; ++j) {
    int row = g * 4 + j;
    float tot = wsum[0][row] + wsum[1][row] + wsum[2][row] + wsum[3][row];
    float sAt = wsumA[0][row] + wsumA[1][row] + wsumA[2][row] + wsumA[3][row];
    float sBt = wsumB[0][row] + wsumB[1][row] + wsumB[2][row] + wsumB[3][row];
    float val = (acc[j] + sAt * t0v + sBt * t128v) / tot;
    int sg = qbase + row;
    vals[((size_t)b * 1024 + sg) * 1024 + h * 64 + dcol] = f2bu(val);
  }
}

// ---------------- output GEMM: out[4096][1024] = vals(bf16) @ owb^T + o_b  (fp32 out)
__global__ __launch_bounds__(256) void gemm_out_k(
    const u16* __restrict__ A, const u16* __restrict__ Bw,
    const float* __restrict__ bias, float* __restrict__ out) {
  __shared__ u16 As[128][40];
  __shared__ u16 Bs[128][40];
  const int tid = threadIdx.x;
  const int l = tid & 63, w = tid >> 6;
  const int wr = w >> 1, wc = w & 1;
  const int fr = l & 15, kq = (l >> 4) * 8;
  const int bid = blockIdx.x;
  const int tn = (bid % 8) * 128, tm = (bid / 8) * 128;
  const int sr = tid >> 1, sc = (tid & 1) * 16;
  const u16* Ag = A + (size_t)(tm + sr) * 1024 + sc;
  const u16* Bg = Bw + (size_t)(tn + sr) * 1024 + sc;
  f32x4 acc[4][4] = {};
  for (int kt = 0; kt < 32; ++kt) {
    bf16x8 a0 = *(const bf16x8*)(Ag + kt * 32);
    bf16x8 a1 = *(const bf16x8*)(Ag + kt * 32 + 8);
    bf16x8 b0 = *(const bf16x8*)(Bg + kt * 32);
    bf16x8 b1 = *(const bf16x8*)(Bg + kt * 32 + 8);
    __syncthreads();
    *(bf16x8*)&As[sr][sc] = a0;
    *(bf16x8*)&As[sr][sc + 8] = a1;
    *(bf16x8*)&Bs[sr][sc] = b0;
    *(bf16x8*)&Bs[sr][sc + 8] = b1;
    __syncthreads();
    bf16x8 af[4], bfv[4];
#pragma unroll
    for (int mi = 0; mi < 4; ++mi) af[mi] = *(const bf16x8*)&As[wr * 64 + mi * 16 + fr][kq];
#pragma unroll
    for (int ni = 0; ni < 4; ++ni) bfv[ni] = *(const bf16x8*)&Bs[wc * 64 + ni * 16 + fr][kq];
#pragma unroll
    for (int mi = 0; mi < 4; ++mi)
#pragma unroll
      for (int ni = 0; ni < 4; ++ni)
        acc[mi][ni] = mfma16(af[mi], bfv[ni], acc[mi][ni]);
  }
#pragma unroll
  for (int mi = 0; mi < 4; ++mi)
#pragma unroll
    for (int ni = 0; ni < 4; ++ni)
#pragma unroll
      for (int j = 0; j < 4; ++j) {
        int gm = tm + wr * 64 + mi * 16 + (l >> 4) * 4 + j;
        int gn = tn + wc * 64 + ni * 16 + fr;
        out[(size_t)gm * 1024 + gn] = acc[mi][ni][j] + bias[gn];
      }
}

extern "C" void kernel_launch(void* const* d_in, const int* in_sizes, int n_in,
                              void* d_out, int out_size, void* d_ws, size_t ws_size,
                              hipStream_t stream) {
  (void)in_sizes; (void)n_in; (void)out_size; (void)ws_size;
  const float* x    = (const float*)d_in[0];
  const float* qkvw = (const float*)d_in[1];
  const float* qkvb = (const float*)d_in[2];
  const float* ow   = (const float*)d_in[3];
  const float* ob   = (const float*)d_in[4];
  const float* tbl  = (const float*)d_in[5];
  const int*   mask = (const int*)d_in[6];
  float* out = (float*)d_out;
  char* ws = (char*)d_ws;
  u16* tb   = (u16*)(ws);
  u16* tbT  = (u16*)(ws + 20480);
  u16* qb   = (u16*)(ws + 40960);
  u16* kb   = (u16*)(ws + 40960 + 8388608ull);
  u16* vt   = (u16*)(ws + 40960 + 2ull * 8388608ull);
  u16* xbvals = (u16*)(ws + 40960 + 3ull * 8388608ull);   // xb (pre-attn) / vals (post)
  u16* bmq  = (u16*)(ws + 40960 + 4ull * 8388608ull);
  u16* wb   = (u16*)(ws + 40960 + 4ull * 8388608ull + 524288ull);
  u16* owb  = (u16*)(ws + 40960 + 4ull * 8388608ull + 524288ull + 6291456ull);

  prep_table_k<<<dim3(1), dim3(256), 0, stream>>>(tbl, tb, tbT);
  prep_maskq_k<<<dim3(1024), dim3(256), 0, stream>>>(mask, bmq);
  prep_bf16_k<<<dim3(2048), dim3(256), 0, stream>>>(x, xbvals, 4194304);
  prep_bf16_k<<<dim3(1536), dim3(256), 0, stream>>>(qkvw, wb, 3145728);
  prep_bf16_k<<<dim3(512), dim3(256), 0, stream>>>(ow, owb, 1048576);
  gemm_qkv_k<<<dim3(768), dim3(256), 0, stream>>>(xbvals, wb, qkvb, qb, kb, vt);
  attn_k<<<dim3(4096), dim3(256), 0, stream>>>(qb, kb, vt, tb, tbT, bmq, xbvals);
  gemm_out_k<<<dim3(256), dim3(256), 0, stream>>>(xbvals, owb, ob, out);
}

// Round 7
// 247.826 us; speedup vs baseline: 1.2242x; 1.0398x over previous
//
#include <hip/hip_runtime.h>

typedef unsigned short u16;
typedef __attribute__((ext_vector_type(8))) short bf16x8;
typedef __attribute__((ext_vector_type(4))) float f32x4;

__device__ __forceinline__ u16 f2bu(float f) {
  union { float f; unsigned u; } v; v.f = f;
  unsigned r = v.u + 0x7fffu + ((v.u >> 16) & 1u);
  return (u16)(r >> 16);
}
__device__ __forceinline__ u16 f2bu_fast(float f) {   // round-half-up, 2 ops
  union { float f; unsigned u; } v; v.f = f;
  return (u16)((v.u + 0x8000u) >> 16);
}
__device__ __forceinline__ float b2f(u16 s) {
  union { unsigned u; float f; } v; v.u = ((unsigned)s) << 16;
  return v.f;
}
__device__ __forceinline__ bf16x8 cvt8(float4 a, float4 b) {
  bf16x8 r;
  r[0] = (short)f2bu(a.x); r[1] = (short)f2bu(a.y);
  r[2] = (short)f2bu(a.z); r[3] = (short)f2bu(a.w);
  r[4] = (short)f2bu(b.x); r[5] = (short)f2bu(b.y);
  r[6] = (short)f2bu(b.z); r[7] = (short)f2bu(b.w);
  return r;
}
__device__ __forceinline__ f32x4 mfma16(bf16x8 a, bf16x8 b, f32x4 c) {
  return __builtin_amdgcn_mfma_f32_16x16x32_bf16(a, b, c, 0, 0, 0);
}

// ---------------- fp32 -> bf16 bulk convert (8 elem/thread)
__global__ __launch_bounds__(256) void prep_bf16_k(const float* __restrict__ src,
                                                   u16* __restrict__ dst, int n) {
  int idx = (blockIdx.x * 256 + threadIdx.x) * 8;
  if (idx < n) {
    float4 a = *(const float4*)(src + idx);
    float4 b = *(const float4*)(src + idx + 4);
    *(bf16x8*)(dst + idx) = cvt8(a, b);
  }
}

// ---------------- table prep: bf16 table [160][64] (pad rows zero) + transpose [64][160]
__global__ void prep_table_k(const float* __restrict__ tbl,
                             u16* __restrict__ tb, u16* __restrict__ tbT) {
  int t = threadIdx.x;
  for (int idx = t; idx < 160 * 64; idx += 256) {
    int r = idx >> 6, d = idx & 63;
    float v = (r < 129) ? tbl[r * 64 + d] : 0.f;
    u16 bv = f2bu(v);
    tb[r * 64 + d] = bv;
    tbT[d * 160 + r] = bv;
  }
}

// ---------------- mask prep: int32 [4][1024][1024] -> transposed 16-bit words
// bmq[b][q][w][fr] bit nt = mask[b][q][w*256 + nt*16 + fr]
__global__ __launch_bounds__(256) void prep_maskq_k(const int* __restrict__ mask,
                                                    u16* __restrict__ bmq) {
  int t = blockIdx.x * 256 + threadIdx.x;     // 262144 total
  int fr = t & 15, wv = (t >> 4) & 3;
  int q = (t >> 6) & 1023, b = t >> 16;
  const int* mrow = mask + ((size_t)b * 1024 + q) * 1024 + wv * 256 + fr;
  unsigned bits = 0;
#pragma unroll
  for (int nt = 0; nt < 16; ++nt) bits |= (mrow[nt * 16] != 0 ? 1u : 0u) << nt;
  bmq[t] = (u16)bits;
}

// ---------------- QKV GEMM (bf16 in): C[4096][3072] = xb @ wb^T + b, scatter q/k/v
// reg double-buffered staging: issue next K-step loads BEFORE the MFMA phase
__global__ __launch_bounds__(256) void gemm_qkv_k(
    const u16* __restrict__ A, const u16* __restrict__ Bw,
    const float* __restrict__ bias,
    u16* __restrict__ qb, u16* __restrict__ kb, u16* __restrict__ vt) {
  __shared__ u16 As[128][40];
  __shared__ u16 Bs[128][40];
  const int tid = threadIdx.x;
  const int l = tid & 63, w = tid >> 6;
  const int wr = w >> 1, wc = w & 1;
  const int fr = l & 15, kq = (l >> 4) * 8;
  const int bid = blockIdx.x;
  const int tn = (bid % 24) * 128, tm = (bid / 24) * 128;
  const int sr = tid >> 1, sc = (tid & 1) * 16;
  const u16* Ag = A + (size_t)(tm + sr) * 1024 + sc;
  const u16* Bg = Bw + (size_t)(tn + sr) * 1024 + sc;
  f32x4 acc[4][4] = {};
  auto compute = [&]() {
    bf16x8 af[4], bfv[4];
#pragma unroll
    for (int mi = 0; mi < 4; ++mi) af[mi] = *(const bf16x8*)&As[wr * 64 + mi * 16 + fr][kq];
#pragma unroll
    for (int ni = 0; ni < 4; ++ni) bfv[ni] = *(const bf16x8*)&Bs[wc * 64 + ni * 16 + fr][kq];
#pragma unroll
    for (int mi = 0; mi < 4; ++mi)
#pragma unroll
      for (int ni = 0; ni < 4; ++ni)
        acc[mi][ni] = mfma16(af[mi], bfv[ni], acc[mi][ni]);
  };
  bf16x8 aX0, aX1, bX0, bX1, aY0, aY1, bY0, bY1;
  aX0 = *(const bf16x8*)(Ag);     aX1 = *(const bf16x8*)(Ag + 8);
  bX0 = *(const bf16x8*)(Bg);     bX1 = *(const bf16x8*)(Bg + 8);
#pragma unroll 1
  for (int kt = 0; kt < 32; kt += 2) {
    __syncthreads();
    *(bf16x8*)&As[sr][sc] = aX0; *(bf16x8*)&As[sr][sc + 8] = aX1;
    *(bf16x8*)&Bs[sr][sc] = bX0; *(bf16x8*)&Bs[sr][sc + 8] = bX1;
    __syncthreads();
    aY0 = *(const bf16x8*)(Ag + (kt + 1) * 32);
    aY1 = *(const bf16x8*)(Ag + (kt + 1) * 32 + 8);
    bY0 = *(const bf16x8*)(Bg + (kt + 1) * 32);
    bY1 = *(const bf16x8*)(Bg + (kt + 1) * 32 + 8);
    compute();
    __syncthreads();
    *(bf16x8*)&As[sr][sc] = aY0; *(bf16x8*)&As[sr][sc + 8] = aY1;
    *(bf16x8*)&Bs[sr][sc] = bY0; *(bf16x8*)&Bs[sr][sc + 8] = bY1;
    __syncthreads();
    if (kt + 2 < 32) {
      aX0 = *(const bf16x8*)(Ag + (kt + 2) * 32);
      aX1 = *(const bf16x8*)(Ag + (kt + 2) * 32 + 8);
      bX0 = *(const bf16x8*)(Bg + (kt + 2) * 32);
      bX1 = *(const bf16x8*)(Bg + (kt + 2) * 32 + 8);
    }
    compute();
  }
#pragma unroll
  for (int mi = 0; mi < 4; ++mi)
#pragma unroll
    for (int ni = 0; ni < 4; ++ni)
#pragma unroll
      for (int j = 0; j < 4; ++j) {
        int gm = tm + wr * 64 + mi * 16 + (l >> 4) * 4 + j;
        int gn = tn + wc * 64 + ni * 16 + fr;
        float v = acc[mi][ni][j] + bias[gn];
        int b = gm >> 10, s = gm & 1023;
        unsigned gnu = (unsigned)gn;
        unsigned h = gnu / 192u;
        unsigned rem = gnu - h * 192u;
        unsigned which = rem >> 6, d = rem & 63u;
        int bh = b * 16 + (int)h;
        u16 bv = f2bu(v);
        if (which == 0u)      qb[((size_t)bh * 1024 + s) * 64 + d] = bv;
        else if (which == 1u) kb[((size_t)bh * 1024 + s) * 64 + d] = bv;
        else                  vt[((size_t)bh * 64 + d) * 1024 + s] = bv;
      }
}

// ---------------- attention: 1 block = (b,h, 16 q-rows); 4 waves
#define PSTR 1032   // p-row stride u16: 2064B = 129 16B slots (odd -> conflict-free)
#define SSTR 136    // qs row stride u16: 272B = 17 slots (odd)
__global__ __launch_bounds__(256) void attn_k(
    const u16* __restrict__ qb, const u16* __restrict__ kb,
    const u16* __restrict__ vt, const u16* __restrict__ tb,
    const u16* __restrict__ tbT, const u16* __restrict__ bmq,
    u16* __restrict__ vals) {
  __shared__ u16 pb[16 * PSTR];        // p~ (unnormalized, bf16)
  __shared__ u16 qs[16 * SSTR];        // pass0-1: qrel (bf16); pass2-3: band region
  __shared__ float wsum[4][16], wsumA[4][16], wsumB[4][16];
  const int tid = threadIdx.x;
  const int l = tid & 63, w = tid >> 6;
  const int fr = l & 15, g = l >> 4, kq = g * 8;
  const int blk = ((int)blockIdx.x & 7) * 512 + ((int)blockIdx.x >> 3);  // XCD swizzle
  const int qt = blk & 63, bh = blk >> 6;
  const int b = bh >> 4, h = bh & 15;
  const int qbase = qt * 16;
  const u16* qrow = qb + ((size_t)bh * 1024 + qbase) * 64;
  bf16x8 qa0 = *(const bf16x8*)(qrow + fr * 64 + kq);
  bf16x8 qa1 = *(const bf16x8*)(qrow + fr * 64 + 32 + kq);
  // mask bits: per row j, 16-bit word (bit nt = col w*256+nt*16+fr)
  unsigned bits[4];
#pragma unroll
  for (int j = 0; j < 4; ++j)
    bits[j] = bmq[(((size_t)b * 1024 + qbase + g * 4 + j) * 4 + w) * 16 + fr];
  // rank-1 table values for r=0 / r=128
  const int dcol = w * 16 + fr;
  const float t0v = b2f(tb[dcol]);
  const float t128v = b2f(tb[128 * 64 + dcol]);
  // K base + early issue of first K pair (consumed in pass 1)
  const u16* kbase = kb + (size_t)bh * 65536;
  auto ldK = [&](int nt, bf16x8& lo, bf16x8& hi) {
    const u16* kp = kbase + (size_t)(w * 256 + nt * 16 + fr) * 64 + kq;
    lo = *(const bf16x8*)(kp);
    hi = *(const bf16x8*)(kp + 32);
  };
  bf16x8 xa0, xa1, xb0, xb1, ya0, ya1, yb0, yb1;
  ldK(0, xa0, xa1); ldK(1, xb0, xb1);
  // pass 0: qrel[row][r] = q . table[r]  (stored bf16 in qs)
  for (int t = w; t < 9; t += 4) {
    int r0 = t * 16;
    const u16* tp = tb + (r0 + fr) * 64 + kq;
    bf16x8 tb0 = *(const bf16x8*)(tp);
    bf16x8 tb1 = *(const bf16x8*)(tp + 32);
    f32x4 acc = {0.f, 0.f, 0.f, 0.f};
    acc = mfma16(qa0, tb0, acc);
    acc = mfma16(qa1, tb1, acc);
    int rg = r0 + fr;
    if (rg < 129) {
#pragma unroll
      for (int j = 0; j < 4; ++j) qs[(g * 4 + j) * SSTR + rg] = f2bu(acc[j]);
    }
  }
  __syncthreads();
  // hoist qrel saturated values (r=0 / r=128) into registers
  float q0r[4], q128r[4];
#pragma unroll
  for (int j = 0; j < 4; ++j) {
    int row = g * 4 + j;
    q0r[j] = b2f(qs[row * SSTR]);
    q128r[j] = b2f(qs[row * SSTR + 128]);
  }
  // pass 1: QK^T + rel + mask + exp2; ROLLED loop, X/Y chunk rotation, depth-1
  const float C1 = 0.18033688011112042f;   // 0.125*log2(e)
  const float C2 = 17.31234049066756f;     // 12*log2(e)
  float ps[4] = {0.f, 0.f, 0.f, 0.f};
  float psA[4] = {0.f, 0.f, 0.f, 0.f};
  float psB[4] = {0.f, 0.f, 0.f, 0.f};
  auto tileC = [&](int nt, bf16x8 k0, bf16x8 k1) {
    int ncol = w * 256 + nt * 16;
    int kgl = ncol + fr;
    f32x4 acc = {0.f, 0.f, 0.f, 0.f};
    acc = mfma16(qa0, k0, acc);
    acc = mfma16(qa1, k1, acc);
    if (ncol + 79 <= qbase) {            // whole tile: dd <= -64 -> rdx = 0
#pragma unroll
      for (int j = 0; j < 4; ++j) {
        float s = acc[j] + q0r[j];
        float arg = ((bits[j] >> nt) & 1u) ? __builtin_fmaf(s, C1, -C2) : -1e30f;
        float e = __builtin_amdgcn_exp2f(arg);
        ps[j] += e; psA[j] += e;
        pb[(g * 4 + j) * PSTR + kgl] = f2bu_fast(e);
      }
    } else if (ncol >= qbase + 79) {     // whole tile: dd >= 64 -> rdx = 128
#pragma unroll
      for (int j = 0; j < 4; ++j) {
        float s = acc[j] + q128r[j];
        float arg = ((bits[j] >> nt) & 1u) ? __builtin_fmaf(s, C1, -C2) : -1e30f;
        float e = __builtin_amdgcn_exp2f(arg);
        ps[j] += e; psB[j] += e;
        pb[(g * 4 + j) * PSTR + kgl] = f2bu_fast(e);
      }
    } else {                              // mixed tile: per-element rdx
#pragma unroll
      for (int j = 0; j < 4; ++j) {
        int row = g * 4 + j;
        int q = qbase + row;
        int dd = kgl - q;
        int rdx = dd < -64 ? 0 : (dd > 64 ? 128 : dd + 64);
        bool ov = (q >= 1 && q <= 1022);
        if (ov && kgl == 0) rdx = 0;
        if (ov && kgl == 1023) rdx = 128;
        float s = acc[j] + b2f(qs[row * SSTR + rdx]);
        float arg = ((bits[j] >> nt) & 1u) ? __builtin_fmaf(s, C1, -C2) : -1e30f;
        float e = __builtin_amdgcn_exp2f(arg);
        ps[j] += e;
        psA[j] += (rdx == 0) ? e : 0.f;
        psB[j] += (rdx == 128) ? e : 0.f;
        pb[row * PSTR + kgl] = f2bu_fast(e);
      }
    }
  };
  {
#pragma unroll 1
    for (int cp = 0; cp < 4; ++cp) {
      int base = cp * 4;
      ldK(base + 2, ya0, ya1); ldK(base + 3, yb0, yb1);
      tileC(base + 0, xa0, xa1); tileC(base + 1, xb0, xb1);
      if (cp < 3) { ldK(base + 4, xa0, xa1); ldK(base + 5, xb0, xb1); }
      tileC(base + 2, ya0, ya1); tileC(base + 3, yb0, yb1);
    }
  }
#pragma unroll
  for (int j = 0; j < 4; ++j) {
#pragma unroll
    for (int off = 1; off <= 8; off <<= 1) {
      ps[j] += __shfl_xor(ps[j], off);
      psA[j] += __shfl_xor(psA[j], off);
      psB[j] += __shfl_xor(psB[j], off);
    }
  }
  if (fr == 0) {
#pragma unroll
    for (int j = 0; j < 4; ++j) {
      wsum[w][g * 4 + j] = ps[j];
      wsumA[w][g * 4 + j] = psA[j];
      wsumB[w][g * 4 + j] = psB[j];
    }
  }
  // early issue: first V chunk + table-T fragments (consumed in pass 3;
  // latency hidden under the barrier + pass 2)
  const u16* vbase = vt + (size_t)bh * 65536;
  const u16* arow = pb + fr * PSTR + kq;
  const u16* vrow = vbase + (size_t)dcol * 1024 + kq;
  bf16x8 tf0 = *(const bf16x8*)(tbT + dcol * 160 + kq);
  bf16x8 tf1 = *(const bf16x8*)(tbT + dcol * 160 + kq + 32);
  bf16x8 tf2 = *(const bf16x8*)(tbT + dcol * 160 + kq + 64);
  bf16x8 tf3 = *(const bf16x8*)(tbT + dcol * 160 + kq + 96);
  bf16x8 x0 = *(const bf16x8*)(vrow);
  bf16x8 x1 = *(const bf16x8*)(vrow + 32);
  bf16x8 x2 = *(const bf16x8*)(vrow + 64);
  bf16x8 x3 = *(const bf16x8*)(vrow + 96);
  __syncthreads();   // qrel reads done -> qs reusable as band buffer
  // pass 2: fully parallel band gather into qs (r=0 zero; overridden edges zero)
  {
    int row2 = tid >> 4;
    int rb = (tid & 15) * 8;
    int q2 = qbase + row2;
    bool ov2 = (q2 >= 1 && q2 <= 1022);
    bf16x8 tmp;
#pragma unroll
    for (int i = 0; i < 8; ++i) {
      int r = rb + i;
      int k = q2 - 64 + r;
      int ksafe = k < 0 ? 0 : (k > 1023 ? 1023 : k);
      u16 val = pb[row2 * PSTR + ksafe];
      bool zero = (r == 0) || (k < 0) || (k > 1023) || (ov2 && (k == 0 || k == 1023));
      tmp[i] = zero ? (short)0 : (short)val;
    }
    *(bf16x8*)&qs[row2 * SSTR + rb] = tmp;
    if (tid < 16) {
      bf16x8 z = {};
      *(bf16x8*)&qs[tid * SSTR + 128] = z;
    }
  }
  __syncthreads();
  // pass 3: PV (p~ x V^T) + band (s~ x table) + rank-1 r=0/128, scale by 1/sum
  f32x4 acc = {0.f, 0.f, 0.f, 0.f};
  {
    bf16x8 y0, y1, y2, y3;
#pragma unroll 1
    for (int cp = 0; cp < 4; ++cp) {
      int base = cp * 8;
      y0 = *(const bf16x8*)(vrow + (base + 4) * 32);
      y1 = *(const bf16x8*)(vrow + (base + 5) * 32);
      y2 = *(const bf16x8*)(vrow + (base + 6) * 32);
      y3 = *(const bf16x8*)(vrow + (base + 7) * 32);
      acc = mfma16(*(const bf16x8*)(arow + (base + 0) * 32), x0, acc);
      acc = mfma16(*(const bf16x8*)(arow + (base + 1) * 32), x1, acc);
      acc = mfma16(*(const bf16x8*)(arow + (base + 2) * 32), x2, acc);
      acc = mfma16(*(const bf16x8*)(arow + (base + 3) * 32), x3, acc);
      if (cp < 3) {
        x0 = *(const bf16x8*)(vrow + (base + 8) * 32);
        x1 = *(const bf16x8*)(vrow + (base + 9) * 32);
        x2 = *(const bf16x8*)(vrow + (base + 10) * 32);
        x3 = *(const bf16x8*)(vrow + (base + 11) * 32);
      }
      acc = mfma16(*(const bf16x8*)(arow + (base + 4) * 32), y0, acc);
      acc = mfma16(*(const bf16x8*)(arow + (base + 5) * 32), y1, acc);
      acc = mfma16(*(const bf16x8*)(arow + (base + 6) * 32), y2, acc);
      acc = mfma16(*(const bf16x8*)(arow + (base + 7) * 32), y3, acc);
    }
  }
  const u16* srow = qs + fr * SSTR + kq;
  acc = mfma16(*(const bf16x8*)(srow), tf0, acc);
  acc = mfma16(*(const bf16x8*)(srow + 32), tf1, acc);
  acc = mfma16(*(const bf16x8*)(srow + 64), tf2, acc);
  acc = mfma16(*(const bf16x8*)(srow + 96), tf3, acc);
#pragma unroll
  for (int j = 0; j < 4; ++j) {
    int row = g * 4 + j;
    float tot = wsum[0][row] + wsum[1][row] + wsum[2][row] + wsum[3][row];
    float sAt = wsumA[0][row] + wsumA[1][row] + wsumA[2][row] + wsumA[3][row];
    float sBt = wsumB[0][row] + wsumB[1][row] + wsumB[2][row] + wsumB[3][row];
    float val = (acc[j] + sAt * t0v + sBt * t128v) / tot;
    int sg = qbase + row;
    vals[((size_t)b * 1024 + sg) * 1024 + h * 64 + dcol] = f2bu(val);
  }
}

// ---------------- output GEMM: out[4096][1024] = vals(bf16) @ owb^T + o_b  (fp32 out)
__global__ __launch_bounds__(256) void gemm_out_k(
    const u16* __restrict__ A, const u16* __restrict__ Bw,
    const float* __restrict__ bias, float* __restrict__ out) {
  __shared__ u16 As[128][40];
  __shared__ u16 Bs[128][40];
  const int tid = threadIdx.x;
  const int l = tid & 63, w = tid >> 6;
  const int wr = w >> 1, wc = w & 1;
  const int fr = l & 15, kq = (l >> 4) * 8;
  const int bid = blockIdx.x;
  const int tn = (bid % 8) * 128, tm = (bid / 8) * 128;
  const int sr = tid >> 1, sc = (tid & 1) * 16;
  const u16* Ag = A + (size_t)(tm + sr) * 1024 + sc;
  const u16* Bg = Bw + (size_t)(tn + sr) * 1024 + sc;
  f32x4 acc[4][4] = {};
  auto compute = [&]() {
    bf16x8 af[4], bfv[4];
#pragma unroll
    for (int mi = 0; mi < 4; ++mi) af[mi] = *(const bf16x8*)&As[wr * 64 + mi * 16 + fr][kq];
#pragma unroll
    for (int ni = 0; ni < 4; ++ni) bfv[ni] = *(const bf16x8*)&Bs[wc * 64 + ni * 16 + fr][kq];
#pragma unroll
    for (int mi = 0; mi < 4; ++mi)
#pragma unroll
      for (int ni = 0; ni < 4; ++ni)
        acc[mi][ni] = mfma16(af[mi], bfv[ni], acc[mi][ni]);
  };
  bf16x8 aX0, aX1, bX0, bX1, aY0, aY1, bY0, bY1;
  aX0 = *(const bf16x8*)(Ag);     aX1 = *(const bf16x8*)(Ag + 8);
  bX0 = *(const bf16x8*)(Bg);     bX1 = *(const bf16x8*)(Bg + 8);
#pragma unroll 1
  for (int kt = 0; kt < 32; kt += 2) {
    __syncthreads();
    *(bf16x8*)&As[sr][sc] = aX0; *(bf16x8*)&As[sr][sc + 8] = aX1;
    *(bf16x8*)&Bs[sr][sc] = bX0; *(bf16x8*)&Bs[sr][sc + 8] = bX1;
    __syncthreads();
    aY0 = *(const bf16x8*)(Ag + (kt + 1) * 32);
    aY1 = *(const bf16x8*)(Ag + (kt + 1) * 32 + 8);
    bY0 = *(const bf16x8*)(Bg + (kt + 1) * 32);
    bY1 = *(const bf16x8*)(Bg + (kt + 1) * 32 + 8);
    compute();
    __syncthreads();
    *(bf16x8*)&As[sr][sc] = aY0; *(bf16x8*)&As[sr][sc + 8] = aY1;
    *(bf16x8*)&Bs[sr][sc] = bY0; *(bf16x8*)&Bs[sr][sc + 8] = bY1;
    __syncthreads();
    if (kt + 2 < 32) {
      aX0 = *(const bf16x8*)(Ag + (kt + 2) * 32);
      aX1 = *(const bf16x8*)(Ag + (kt + 2) * 32 + 8);
      bX0 = *(const bf16x8*)(Bg + (kt + 2) * 32);
      bX1 = *(const bf16x8*)(Bg + (kt + 2) * 32 + 8);
    }
    compute();
  }
#pragma unroll
  for (int mi = 0; mi < 4; ++mi)
#pragma unroll
    for (int ni = 0; ni < 4; ++ni)
#pragma unroll
      for (int j = 0; j < 4; ++j) {
        int gm = tm + wr * 64 + mi * 16 + (l >> 4) * 4 + j;
        int gn = tn + wc * 64 + ni * 16 + fr;
        out[(size_t)gm * 1024 + gn] = acc[mi][ni][j] + bias[gn];
      }
}

extern "C" void kernel_launch(void* const* d_in, const int* in_sizes, int n_in,
                              void* d_out, int out_size, void* d_ws, size_t ws_size,
                              hipStream_t stream) {
  (void)in_sizes; (void)n_in; (void)out_size; (void)ws_size;
  const float* x    = (const float*)d_in[0];
  const float* qkvw = (const float*)d_in[1];
  const float* qkvb = (const float*)d_in[2];
  const float* ow   = (const float*)d_in[3];
  const float* ob   = (const float*)d_in[4];
  const float* tbl  = (const float*)d_in[5];
  const int*   mask = (const int*)d_in[6];
  float* out = (float*)d_out;
  char* ws = (char*)d_ws;
  u16* tb   = (u16*)(ws);
  u16* tbT  = (u16*)(ws + 20480);
  u16* qb   = (u16*)(ws + 40960);
  u16* kb   = (u16*)(ws + 40960 + 8388608ull);
  u16* vt   = (u16*)(ws + 40960 + 2ull * 8388608ull);
  u16* xbvals = (u16*)(ws + 40960 + 3ull * 8388608ull);   // xb (pre-attn) / vals (post)
  u16* bmq  = (u16*)(ws + 40960 + 4ull * 8388608ull);
  u16* wb   = (u16*)(ws + 40960 + 4ull * 8388608ull + 524288ull);
  u16* owb  = (u16*)(ws + 40960 + 4ull * 8388608ull + 524288ull + 6291456ull);

  prep_table_k<<<dim3(1), dim3(256), 0, stream>>>(tbl, tb, tbT);
  prep_maskq_k<<<dim3(1024), dim3(256), 0, stream>>>(mask, bmq);
  prep_bf16_k<<<dim3(2048), dim3(256), 0, stream>>>(x, xbvals, 4194304);
  prep_bf16_k<<<dim3(1536), dim3(256), 0, stream>>>(qkvw, wb, 3145728);
  prep_bf16_k<<<dim3(512), dim3(256), 0, stream>>>(ow, owb, 1048576);
  gemm_qkv_k<<<dim3(768), dim3(256), 0, stream>>>(xbvals, wb, qkvb, qb, kb, vt);
  attn_k<<<dim3(4096), dim3(256), 0, stream>>>(qb, kb, vt, tb, tbT, bmq, xbvals);
  gemm_out_k<<<dim3(256), dim3(256), 0, stream>>>(xbvals, owb, ob, out);
}